// Round 1
// baseline (62.151 us; speedup 1.0000x reference)
//
#include <hip/hip_runtime.h>

#define EPSILON 0.1f

__device__ __constant__ float ETA_FAULT[12][4] = {
    {0.99997f, -1.0f, 0.0f, 9.1182e-18f},
    {-0.55856f, -1.0f, 0.0f, -3.7472e-10f},
    {-16.919f, 14.562f, 0.086479f, 82.578f},
    {1.0f, -1.0f, 0.0f, 4.4982e-16f},
    {1.6839f, -2.2404f, -2.5173f, 1.1147f},
    {-0.55856f, -1.0f, 0.0f, -3.7472e-10f},
    {0.99997f, -1.0f, 0.0f, 9.1182e-18f},
    {0.23198f, -0.78334f, -0.41194f, 3.4699f},
    {1.0f, -1.0f, 0.0f, 4.4982e-16f},
    {0.99997f, -1.0f, 0.0f, 9.1182e-18f},
    {-0.24548f, -0.02379f, 0.81499f, 1.5337f},
    {-1.0f, -1.0f, 0.0f, 4.407e-16f}
};

// ---------------------------------------------------------------------------
// Kernel A: compute eta[n][i] for n in [0,64), i in [0,4).  Tiny — 1 block.
// ---------------------------------------------------------------------------
__global__ void eta_kernel(const float* __restrict__ rt_,
                           const float* __restrict__ noise,
                           const float* __restrict__ X_max,
                           const float* __restrict__ X_min,
                           const float* __restrict__ Y_max,
                           const float* __restrict__ Y_min,
                           const float* __restrict__ W1,
                           const float* __restrict__ b1,
                           const float* __restrict__ W2,
                           const float* __restrict__ b2,
                           float* __restrict__ eta_out) {
    const int n = threadIdx.x;  // 64 threads, one per N row

    float RTv[6];
    #pragma unroll
    for (int k = 0; k < 6; ++k) {
        float s  = 1.0f / (1.0f + expf(-rt_[k]));           // sigmoid(rt_)
        float RT = s * (X_max[k] - X_min[k]) + X_min[k];
        float nf = (noise[n * 9 + k] * 2.0f - 1.0f) * EPSILON + 1.0f;
        RTv[k] = RT * nf;
    }
    float ext[9];
    #pragma unroll
    for (int k = 0; k < 6; ++k) ext[k] = RTv[k];
    ext[6] = RTv[1] / RTv[0];
    ext[7] = RTv[3] / RTv[2];
    ext[8] = RTv[5] / RTv[4];

    float xn[9];
    #pragma unroll
    for (int k = 0; k < 9; ++k)
        xn[k] = (ext[k] - X_min[k]) / (X_max[k] - X_min[k]);

    float a0 = b2[0], a1 = b2[1], a2 = b2[2], a3 = b2[3];
    for (int j = 0; j < 64; ++j) {
        float hj = b1[j];
        #pragma unroll
        for (int k = 0; k < 9; ++k) hj += xn[k] * W1[k * 64 + j];
        hj = fmaxf(hj, 0.0f);  // relu
        a0 += hj * W2[j * 4 + 0];
        a1 += hj * W2[j * 4 + 1];
        a2 += hj * W2[j * 4 + 2];
        a3 += hj * W2[j * 4 + 3];
    }
    float ys[4] = {a0, a1, a2, a3};
    #pragma unroll
    for (int i = 0; i < 4; ++i) {
        float s = 1.0f / (1.0f + expf(-ys[i]));              // sigmoid
        eta_out[n * 4 + i] = s * (Y_max[i] - Y_min[i]) + Y_min[i];
    }
}

// ---------------------------------------------------------------------------
// Kernel B: out[m,n,b,c] = e0 + e1 * tanh((z - e2) * e3), params per (m,n,c).
// Thread t owns 4 consecutive c columns (one float4); params hoisted to regs.
// ---------------------------------------------------------------------------
__device__ __forceinline__ float tanh_fast(float x) {
    float e = __expf(2.0f * x);
    return 1.0f - __fdividef(2.0f, e + 1.0f);
}

__global__ __launch_bounds__(256) void tanhrt_main(
    const float* __restrict__ z,
    const int* __restrict__ mask,
    const float* __restrict__ eta,
    float* __restrict__ out) {
    // grid = M*N*8 = 2048 blocks; each block: (m,n) slab, 32 rows of b.
    const int t      = threadIdx.x;
    const int blk    = blockIdx.x;
    const int bchunk = blk & 7;        // which 32-row chunk of B=256
    const int mn     = blk >> 3;       // m*64 + n
    const int n      = mn & 63;
    const int m      = mn >> 6;
    const int c0     = (t & 127) << 2; // starting c of this thread's float4
    const int rsel   = t >> 7;         // 0 or 1: which of 2 rows per iter

    // Hoist the 4 parameter quadruples (one per owned c) into registers.
    float p0[4], p1[4], p2[4], p3[4];
    #pragma unroll
    for (int j = 0; j < 4; ++j) {
        int mk = mask[m * 512 + c0 + j];
        const float* src = (mk == 0) ? (eta + n * 4) : &ETA_FAULT[mk - 1][0];
        p0[j] = src[0];
        p1[j] = src[1];
        p2[j] = src[2];
        p3[j] = src[3];
    }

    size_t base = (((size_t)mn * 256) + (size_t)bchunk * 32) * 512 + c0;
    #pragma unroll 4
    for (int b = rsel; b < 32; b += 2) {
        size_t idx = base + (size_t)b * 512;
        float4 zv = *reinterpret_cast<const float4*>(z + idx);
        float4 o;
        o.x = p0[0] + p1[0] * tanh_fast((zv.x - p2[0]) * p3[0]);
        o.y = p0[1] + p1[1] * tanh_fast((zv.y - p2[1]) * p3[1]);
        o.z = p0[2] + p1[2] * tanh_fast((zv.z - p2[2]) * p3[2]);
        o.w = p0[3] + p1[3] * tanh_fast((zv.w - p2[3]) * p3[3]);
        *reinterpret_cast<float4*>(out + idx) = o;
    }
}

extern "C" void kernel_launch(void* const* d_in, const int* in_sizes, int n_in,
                              void* d_out, int out_size, void* d_ws, size_t ws_size,
                              hipStream_t stream) {
    const float* z     = (const float*)d_in[0];
    const float* rt    = (const float*)d_in[1];
    const float* noise = (const float*)d_in[2];
    const float* X_max = (const float*)d_in[3];
    const float* X_min = (const float*)d_in[4];
    const float* Y_max = (const float*)d_in[5];
    const float* Y_min = (const float*)d_in[6];
    const float* W1    = (const float*)d_in[7];
    const float* b1    = (const float*)d_in[8];
    const float* W2    = (const float*)d_in[9];
    const float* b2    = (const float*)d_in[10];
    const int*   mask  = (const int*)d_in[11];
    float* out = (float*)d_out;
    float* eta = (float*)d_ws;  // 64*4 floats = 1 KiB

    eta_kernel<<<1, 64, 0, stream>>>(rt, noise, X_max, X_min, Y_max, Y_min,
                                     W1, b1, W2, b2, eta);
    tanhrt_main<<<2048, 256, 0, stream>>>(z, mask, eta, out);
}

// Round 3
// 47.081 us; speedup vs baseline: 1.3201x; 1.3201x over previous
//
#include <hip/hip_runtime.h>

#define EPSILON 0.1f

typedef float f32x4 __attribute__((ext_vector_type(4)));

__device__ __constant__ float ETA_FAULT[12][4] = {
    {0.99997f, -1.0f, 0.0f, 9.1182e-18f},
    {-0.55856f, -1.0f, 0.0f, -3.7472e-10f},
    {-16.919f, 14.562f, 0.086479f, 82.578f},
    {1.0f, -1.0f, 0.0f, 4.4982e-16f},
    {1.6839f, -2.2404f, -2.5173f, 1.1147f},
    {-0.55856f, -1.0f, 0.0f, -3.7472e-10f},
    {0.99997f, -1.0f, 0.0f, 9.1182e-18f},
    {0.23198f, -0.78334f, -0.41194f, 3.4699f},
    {1.0f, -1.0f, 0.0f, 4.4982e-16f},
    {0.99997f, -1.0f, 0.0f, 9.1182e-18f},
    {-0.24548f, -0.02379f, 0.81499f, 1.5337f},
    {-1.0f, -1.0f, 0.0f, 4.407e-16f}
};

__device__ __forceinline__ float tanh_fast(float x) {
    float e = __expf(2.0f * x);
    return 1.0f - __fdividef(2.0f, e + 1.0f);
}

// ---------------------------------------------------------------------------
// Fused kernel: first wave computes eta[n] (the tiny MLP) via shuffle-reduce,
// broadcast through LDS; then all 256 threads stream the (m,n) slab.
// grid = M*N*8 = 2048 blocks; each block handles 32 b-rows of one (m,n).
// ---------------------------------------------------------------------------
__global__ __launch_bounds__(256) void tanhrt_fused(
    const float* __restrict__ z,
    const int* __restrict__ mask,
    const float* __restrict__ rt_,
    const float* __restrict__ noise,
    const float* __restrict__ X_max,
    const float* __restrict__ X_min,
    const float* __restrict__ Y_max,
    const float* __restrict__ Y_min,
    const float* __restrict__ W1,
    const float* __restrict__ b1,
    const float* __restrict__ W2,
    const float* __restrict__ b2,
    float* __restrict__ out) {
    const int t      = threadIdx.x;
    const int blk    = blockIdx.x;
    const int bchunk = blk & 7;        // which 32-row chunk of B=256
    const int mn     = blk >> 3;       // m*64 + n
    const int n      = mn & 63;
    const int m      = mn >> 6;

    __shared__ float eta_sh[4];

    // ---- tiny MLP for this block's n (first wave only) ----
    if (t < 64) {
        float xn[9];
        #pragma unroll
        for (int k = 0; k < 6; ++k) {
            float s  = 1.0f / (1.0f + __expf(-rt_[k]));
            float RT = s * (X_max[k] - X_min[k]) + X_min[k];
            float nf = (noise[n * 9 + k] * 2.0f - 1.0f) * EPSILON + 1.0f;
            xn[k] = RT * nf;   // RTv for now
        }
        float e6 = xn[1] / xn[0];
        float e7 = xn[3] / xn[2];
        float e8 = xn[5] / xn[4];
        xn[6] = e6; xn[7] = e7; xn[8] = e8;
        #pragma unroll
        for (int k = 0; k < 9; ++k)
            xn[k] = (xn[k] - X_min[k]) / (X_max[k] - X_min[k]);

        // hidden unit j = lane
        float hj = b1[t];
        #pragma unroll
        for (int k = 0; k < 9; ++k) hj += xn[k] * W1[k * 64 + t];
        hj = fmaxf(hj, 0.0f);
        float a0 = hj * W2[t * 4 + 0];
        float a1 = hj * W2[t * 4 + 1];
        float a2 = hj * W2[t * 4 + 2];
        float a3 = hj * W2[t * 4 + 3];
        #pragma unroll
        for (int off = 32; off; off >>= 1) {
            a0 += __shfl_down(a0, off);
            a1 += __shfl_down(a1, off);
            a2 += __shfl_down(a2, off);
            a3 += __shfl_down(a3, off);
        }
        if (t == 0) {
            float ys[4] = {a0 + b2[0], a1 + b2[1], a2 + b2[2], a3 + b2[3]};
            #pragma unroll
            for (int i = 0; i < 4; ++i) {
                float s = 1.0f / (1.0f + __expf(-ys[i]));
                eta_sh[i] = s * (Y_max[i] - Y_min[i]) + Y_min[i];
            }
        }
    }
    __syncthreads();

    // ---- per-thread parameter hoist (4 consecutive c columns) ----
    const int c0   = (t & 127) << 2;
    const int rsel = t >> 7;           // 0/1: even/odd rows

    float p0[4], p1[4], p2[4], p3[4];
    #pragma unroll
    for (int j = 0; j < 4; ++j) {
        int mk = mask[m * 512 + c0 + j];
        const float* src = (mk == 0) ? eta_sh : &ETA_FAULT[mk - 1][0];
        p0[j] = src[0];
        p1[j] = src[1];
        p2[j] = src[2];
        p3[j] = src[3];
    }

    // ---- streaming main loop: 16 float4 per thread, 2 batches of 8 ----
    size_t base = (((size_t)mn * 256) + (size_t)bchunk * 32 + rsel) * 512 + c0;
    const float* zp = z + base;
    float*       op = out + base;

    #pragma unroll
    for (int half = 0; half < 2; ++half) {
        f32x4 v[8];
        #pragma unroll
        for (int i = 0; i < 8; ++i)
            v[i] = *reinterpret_cast<const f32x4*>(zp + (size_t)(half * 8 + i) * 1024);
        #pragma unroll
        for (int i = 0; i < 8; ++i) {
            f32x4 o;
            o.x = p0[0] + p1[0] * tanh_fast((v[i].x - p2[0]) * p3[0]);
            o.y = p0[1] + p1[1] * tanh_fast((v[i].y - p2[1]) * p3[1]);
            o.z = p0[2] + p1[2] * tanh_fast((v[i].z - p2[2]) * p3[2]);
            o.w = p0[3] + p1[3] * tanh_fast((v[i].w - p2[3]) * p3[3]);
            __builtin_nontemporal_store(o,
                reinterpret_cast<f32x4*>(op + (size_t)(half * 8 + i) * 1024));
        }
    }
}

extern "C" void kernel_launch(void* const* d_in, const int* in_sizes, int n_in,
                              void* d_out, int out_size, void* d_ws, size_t ws_size,
                              hipStream_t stream) {
    const float* z     = (const float*)d_in[0];
    const float* rt    = (const float*)d_in[1];
    const float* noise = (const float*)d_in[2];
    const float* X_max = (const float*)d_in[3];
    const float* X_min = (const float*)d_in[4];
    const float* Y_max = (const float*)d_in[5];
    const float* Y_min = (const float*)d_in[6];
    const float* W1    = (const float*)d_in[7];
    const float* b1    = (const float*)d_in[8];
    const float* W2    = (const float*)d_in[9];
    const float* b2    = (const float*)d_in[10];
    const int*   mask  = (const int*)d_in[11];
    float* out = (float*)d_out;

    tanhrt_fused<<<2048, 256, 0, stream>>>(z, mask, rt, noise,
                                           X_max, X_min, Y_max, Y_min,
                                           W1, b1, W2, b2, out);
}

// Round 4
// 46.328 us; speedup vs baseline: 1.3415x; 1.0162x over previous
//
#include <hip/hip_runtime.h>

#define EPSILON 0.1f

typedef float f32x4 __attribute__((ext_vector_type(4)));

__device__ __constant__ float ETA_FAULT[12][4] = {
    {0.99997f, -1.0f, 0.0f, 9.1182e-18f},
    {-0.55856f, -1.0f, 0.0f, -3.7472e-10f},
    {-16.919f, 14.562f, 0.086479f, 82.578f},
    {1.0f, -1.0f, 0.0f, 4.4982e-16f},
    {1.6839f, -2.2404f, -2.5173f, 1.1147f},
    {-0.55856f, -1.0f, 0.0f, -3.7472e-10f},
    {0.99997f, -1.0f, 0.0f, 9.1182e-18f},
    {0.23198f, -0.78334f, -0.41194f, 3.4699f},
    {1.0f, -1.0f, 0.0f, 4.4982e-16f},
    {0.99997f, -1.0f, 0.0f, 9.1182e-18f},
    {-0.24548f, -0.02379f, 0.81499f, 1.5337f},
    {-1.0f, -1.0f, 0.0f, 4.407e-16f}
};

__device__ __forceinline__ float tanh_fast(float x) {
    float e = __expf(2.0f * x);
    return 1.0f - __fdividef(2.0f, e + 1.0f);
}

// ---------------------------------------------------------------------------
// Fused kernel. grid = M*N*16 = 4096 blocks; each block handles 16 b-rows of
// one (m,n) slab. Each thread: 4 consecutive c columns x 8 rows = one 8-deep
// float4 batch, all loads in flight at once, nt stores.
// ---------------------------------------------------------------------------
__global__ __launch_bounds__(256, 8) void tanhrt_fused(
    const float* __restrict__ z,
    const int* __restrict__ mask,
    const float* __restrict__ rt_,
    const float* __restrict__ noise,
    const float* __restrict__ X_max,
    const float* __restrict__ X_min,
    const float* __restrict__ Y_max,
    const float* __restrict__ Y_min,
    const float* __restrict__ W1,
    const float* __restrict__ b1,
    const float* __restrict__ W2,
    const float* __restrict__ b2,
    float* __restrict__ out) {
    const int t      = threadIdx.x;
    const int blk    = blockIdx.x;
    const int bchunk = blk & 15;       // which 16-row chunk of B=256
    const int mn     = blk >> 4;       // m*64 + n
    const int n      = mn & 63;
    const int m      = mn >> 6;

    __shared__ float eta_sh[4];

    // ---- tiny MLP for this block's n (first wave only) ----
    if (t < 64) {
        float xn[9];
        #pragma unroll
        for (int k = 0; k < 6; ++k) {
            float s  = 1.0f / (1.0f + __expf(-rt_[k]));
            float RT = s * (X_max[k] - X_min[k]) + X_min[k];
            float nf = (noise[n * 9 + k] * 2.0f - 1.0f) * EPSILON + 1.0f;
            xn[k] = RT * nf;   // RTv for now
        }
        float e6 = xn[1] / xn[0];
        float e7 = xn[3] / xn[2];
        float e8 = xn[5] / xn[4];
        xn[6] = e6; xn[7] = e7; xn[8] = e8;
        #pragma unroll
        for (int k = 0; k < 9; ++k)
            xn[k] = (xn[k] - X_min[k]) / (X_max[k] - X_min[k]);

        // hidden unit j = lane
        float hj = b1[t];
        #pragma unroll
        for (int k = 0; k < 9; ++k) hj += xn[k] * W1[k * 64 + t];
        hj = fmaxf(hj, 0.0f);
        float a0 = hj * W2[t * 4 + 0];
        float a1 = hj * W2[t * 4 + 1];
        float a2 = hj * W2[t * 4 + 2];
        float a3 = hj * W2[t * 4 + 3];
        #pragma unroll
        for (int off = 32; off; off >>= 1) {
            a0 += __shfl_down(a0, off);
            a1 += __shfl_down(a1, off);
            a2 += __shfl_down(a2, off);
            a3 += __shfl_down(a3, off);
        }
        if (t == 0) {
            float ys[4] = {a0 + b2[0], a1 + b2[1], a2 + b2[2], a3 + b2[3]};
            #pragma unroll
            for (int i = 0; i < 4; ++i) {
                float s = 1.0f / (1.0f + __expf(-ys[i]));
                eta_sh[i] = s * (Y_max[i] - Y_min[i]) + Y_min[i];
            }
        }
    }
    __syncthreads();

    // ---- per-thread parameter hoist (4 consecutive c columns) ----
    const int c0   = (t & 127) << 2;
    const int rsel = t >> 7;           // 0/1: even/odd rows

    float p0[4], p1[4], p2[4], p3[4];
    #pragma unroll
    for (int j = 0; j < 4; ++j) {
        int mk = mask[m * 512 + c0 + j];
        const float* src = (mk == 0) ? eta_sh : &ETA_FAULT[mk - 1][0];
        p0[j] = src[0];
        p1[j] = src[1];
        p2[j] = src[2];
        p3[j] = src[3];
    }

    // ---- streaming: 8 float4 per thread, single batch, all in flight ----
    size_t base = (((size_t)mn * 256) + (size_t)bchunk * 16 + rsel) * 512 + c0;
    const float* zp = z + base;
    float*       op = out + base;

    f32x4 v[8];
    #pragma unroll
    for (int i = 0; i < 8; ++i)
        v[i] = *reinterpret_cast<const f32x4*>(zp + (size_t)i * 1024);
    #pragma unroll
    for (int i = 0; i < 8; ++i) {
        f32x4 o;
        o.x = p0[0] + p1[0] * tanh_fast((v[i].x - p2[0]) * p3[0]);
        o.y = p0[1] + p1[1] * tanh_fast((v[i].y - p2[1]) * p3[1]);
        o.z = p0[2] + p1[2] * tanh_fast((v[i].z - p2[2]) * p3[2]);
        o.w = p0[3] + p1[3] * tanh_fast((v[i].w - p2[3]) * p3[3]);
        __builtin_nontemporal_store(o,
            reinterpret_cast<f32x4*>(op + (size_t)i * 1024));
    }
}

extern "C" void kernel_launch(void* const* d_in, const int* in_sizes, int n_in,
                              void* d_out, int out_size, void* d_ws, size_t ws_size,
                              hipStream_t stream) {
    const float* z     = (const float*)d_in[0];
    const float* rt    = (const float*)d_in[1];
    const float* noise = (const float*)d_in[2];
    const float* X_max = (const float*)d_in[3];
    const float* X_min = (const float*)d_in[4];
    const float* Y_max = (const float*)d_in[5];
    const float* Y_min = (const float*)d_in[6];
    const float* W1    = (const float*)d_in[7];
    const float* b1    = (const float*)d_in[8];
    const float* W2    = (const float*)d_in[9];
    const float* b2    = (const float*)d_in[10];
    const int*   mask  = (const int*)d_in[11];
    float* out = (float*)d_out;

    tanhrt_fused<<<4096, 256, 0, stream>>>(z, mask, rt, noise,
                                           X_max, X_min, Y_max, Y_min,
                                           W1, b1, W2, b2, out);
}